// Round 7
// baseline (453.087 us; speedup 1.0000x reference)
//
#include <hip/hip_runtime.h>
#include <math.h>

#define NS 8192
#define DS 64
#define HD 4096
#define C2L 2.8853900817779268f   // 2*log2(e)
#define SPB 4                     // samples per block
#define CH 16                     // steps per chunk
#define NCH (DS / CH)
#define PPAD 33                   // parts inner pad (bank-conflict-free chunk reduce)

typedef float v2f __attribute__((ext_vector_type(2)));

__device__ __forceinline__ v2f pk_add(v2f a, v2f b) {
    v2f d; asm("v_pk_add_f32 %0, %1, %2" : "=v"(d) : "v"(a), "v"(b)); return d;
}
__device__ __forceinline__ v2f pk_mul(v2f a, v2f b) {
    v2f d; asm("v_pk_mul_f32 %0, %1, %2" : "=v"(d) : "v"(a), "v"(b)); return d;
}
__device__ __forceinline__ v2f pk_fma(v2f a, v2f b, v2f c) {
    v2f d; asm("v_pk_fma_f32 %0, %1, %2, %3" : "=v"(d) : "v"(a), "v"(b), "v"(c)); return d;
}

__device__ __forceinline__ float fast_tanh(float x) {
    float t = __builtin_amdgcn_exp2f(x * C2L);
    float r = __builtin_amdgcn_rcpf(t + 1.0f);
    return __builtin_fmaf(-2.0f, r, 1.0f);
}

template <int PATT>
__device__ __forceinline__ v2f swz_xor(v2f v) {
    v2f d;
    d.x = __int_as_float(__builtin_amdgcn_ds_swizzle(__float_as_int(v.x), PATT));
    d.y = __int_as_float(__builtin_amdgcn_ds_swizzle(__float_as_int(v.y), PATT));
    return d;
}

// ---- setup: Et[0][d][h]=e^{+2W1}, Et[1][d][h]=e^{-2W1}; C01 = colsum(W2)+b2 ----
__global__ __launch_bounds__(256) void qnade_prep_E(
    const float* __restrict__ W1, float* __restrict__ Et)
{
    int i = blockIdx.x * 256 + threadIdx.x;
    float w = W1[i] * C2L;
    Et[i]           = __builtin_amdgcn_exp2f(w);
    Et[DS * HD + i] = __builtin_amdgcn_exp2f(-w);
}

__global__ __launch_bounds__(256) void qnade_prep_S(
    const float* __restrict__ W2, const float* __restrict__ b2, float* __restrict__ C01)
{
    __shared__ float p0[4], p1[4];
    int tid = threadIdx.x;
    float s0 = 0.0f, s1 = 0.0f;
    for (int h = tid; h < HD; h += 256) {
        float2 w = ((const float2*)W2)[h];
        s0 += w.x; s1 += w.y;
    }
    #pragma unroll
    for (int m = 1; m < 64; m <<= 1) {
        s0 += __shfl_xor(s0, m, 64);
        s1 += __shfl_xor(s1, m, 64);
    }
    if ((tid & 63) == 0) { p0[tid >> 6] = s0; p1[tid >> 6] = s1; }
    __syncthreads();
    if (tid == 0) {
        C01[0] = p0[0] + p0[1] + p0[2] + p0[3] + b2[0];
        C01[1] = p1[0] + p1[1] + p1[2] + p1[3] + b2[1];
    }
}

// ---- main: one block = 4 samples; hidden dim split across all 256 threads ----
// Per step, block needs at most 2 distinct E rows (L1 dedups duplicate loads)
// -> ~2x less L2 traffic; 4 independent per-sample chains give in-wave ILP.
__global__ __launch_bounds__(256, 2) void qnade_main(
    const float* __restrict__ x, const float* __restrict__ b1,
    const float* __restrict__ W2, const float* __restrict__ Et,
    const float* __restrict__ C01, float* __restrict__ out)
{
    __shared__ float2 parts[CH][SPB][PPAD];  // ~16.9 KB
    __shared__ float2 fin[SPB][DS];          // 2 KB

    const int tid  = threadIdx.x;
    const int lane = tid & 63;
    const int wv   = tid >> 6;
    const int n0   = blockIdx.x * SPB;
    const int eb   = tid * 4;               // element base; + q*1024

    // W2 columns as (even,odd)-element pairs
    v2f w20[8], w21[8];
    #pragma unroll
    for (int q = 0; q < 4; ++q) {
        const float4* p = (const float4*)(W2 + 2 * (eb + q * 1024));
        float4 A = p[0], B = p[1];
        w20[2*q]   = (v2f){A.x, A.z};  w21[2*q]   = (v2f){A.y, A.w};
        w20[2*q+1] = (v2f){B.x, B.z};  w21[2*q+1] = (v2f){B.y, B.w};
    }

    // t0 = e^{2*b1} (identical start for all samples)
    v2f tinit[8];
    #pragma unroll
    for (int q = 0; q < 4; ++q) {
        float4 b = *(const float4*)(b1 + eb + q * 1024);
        tinit[2*q]   = (v2f){__builtin_amdgcn_exp2f(b.x * C2L), __builtin_amdgcn_exp2f(b.y * C2L)};
        tinit[2*q+1] = (v2f){__builtin_amdgcn_exp2f(b.z * C2L), __builtin_amdgcn_exp2f(b.w * C2L)};
    }
    v2f t2[SPB][8];
    #pragma unroll
    for (int m = 0; m < SPB; ++m)
        #pragma unroll
        for (int j = 0; j < 8; ++j) t2[m][j] = tinit[j];

    // spin-sign masks, one per sample (wave-uniform scalars)
    unsigned long long msk[SPB];
    #pragma unroll
    for (int m = 0; m < SPB; ++m)
        msk[m] = __ballot(x[(n0 + m) * DS + lane] > 0.0f);

    int d = 0;
    for (int c = 0; c < NCH; ++c) {
        for (int s16 = 0; s16 < CH; ++s16, ++d) {
            #pragma unroll
            for (int m = 0; m < SPB; ++m) {
                const unsigned uoff =
                    (((msk[m] >> d) & 1ull) ? 0u : (unsigned)(DS * HD)) + (unsigned)d * HD;
                const float* E = Et + uoff + eb;
                float4 e0 = *(const float4*)(E);
                float4 e1 = *(const float4*)(E + 1024);
                float4 e2 = *(const float4*)(E + 2048);
                float4 e3 = *(const float4*)(E + 3072);

                // prefix products of (1+t)
                v2f p2[8];
                p2[0] = pk_add(t2[m][0], (v2f){1.0f, 1.0f});
                #pragma unroll
                for (int j = 1; j < 8; ++j) p2[j] = pk_fma(p2[j - 1], t2[m][j], p2[j - 1]);

                float P = p2[7].x * p2[7].y;
                float R = __builtin_amdgcn_rcpf(P);
                v2f RR = (v2f){R * p2[7].y, R * p2[7].x};

                // fused recovery + dot
                v2f acc0, acc1;
                {
                    v2f r = pk_mul(RR, p2[6]);
                    acc0 = pk_mul(r, w20[7]);
                    acc1 = pk_mul(r, w21[7]);
                    RR = pk_fma(RR, t2[m][7], RR);
                }
                #pragma unroll
                for (int j = 6; j >= 1; --j) {
                    v2f r = pk_mul(RR, p2[j - 1]);
                    acc0 = pk_fma(r, w20[j], acc0);
                    acc1 = pk_fma(r, w21[j], acc1);
                    RR = pk_fma(RR, t2[m][j], RR);
                }
                acc0 = pk_fma(RR, w20[0], acc0);
                acc1 = pk_fma(RR, w21[0], acc1);

                // advance state
                t2[m][0] = pk_mul(t2[m][0], (v2f){e0.x, e0.y});
                t2[m][1] = pk_mul(t2[m][1], (v2f){e0.z, e0.w});
                t2[m][2] = pk_mul(t2[m][2], (v2f){e1.x, e1.y});
                t2[m][3] = pk_mul(t2[m][3], (v2f){e1.z, e1.w});
                t2[m][4] = pk_mul(t2[m][4], (v2f){e2.x, e2.y});
                t2[m][5] = pk_mul(t2[m][5], (v2f){e2.z, e2.w});
                t2[m][6] = pk_mul(t2[m][6], (v2f){e3.x, e3.y});
                t2[m][7] = pk_mul(t2[m][7], (v2f){e3.z, e3.w});

                // dead-end partial reduce (off the recurrence path):
                // 3 swizzle levels -> every 8th lane holds an 8-lane sum
                v2f s = (v2f){acc0.x + acc0.y, acc1.x + acc1.y};
                s = pk_add(s, swz_xor<0x041F>(s));   // xor 1
                s = pk_add(s, swz_xor<0x081F>(s));   // xor 2
                s = pk_add(s, swz_xor<0x101F>(s));   // xor 4
                if ((lane & 7) == 0)
                    parts[s16][m][wv * 8 + (lane >> 3)] = make_float2(s.x, s.y);
            }
        }

        __syncthreads();
        // chunk reduce: 64 (step,sample) units x 32 partials; 4 threads/unit
        {
            const int u = tid >> 2;          // 0..63
            const int j = tid & 3;
            const int sm = u & (CH - 1);     // step-in-chunk
            const int m  = u >> 4;           // sample
            v2f s = (v2f){0.0f, 0.0f};
            #pragma unroll
            for (int i = 0; i < 8; ++i) {
                float2 v = parts[sm][m][j * 8 + i];
                s = pk_add(s, (v2f){v.x, v.y});
            }
            s = pk_add(s, swz_xor<0x041F>(s));
            s = pk_add(s, swz_xor<0x081F>(s));
            if (j == 0) fin[m][c * CH + sm] = make_float2(s.x, s.y);
        }
        __syncthreads();
    }

    // deferred epilogue: wave wv owns sample wv; lane = step
    {
        const int m = wv;
        float2 sv = fin[m][lane];
        float dot0 = __builtin_fmaf(-2.0f, sv.x, C01[0]);
        float dot1 = __builtin_fmaf(-2.0f, sv.y, C01[1]);
        float o0 = fast_tanh(dot0);
        float o1 = fast_tanh(dot1);
        float nrm = sqrtf(__builtin_fmaf(o0, o0, o1 * o1));
        nrm = fmaxf(nrm, 1e-12f);
        bool pos = (msk[m] >> lane) & 1ull;
        float sel = pos ? o0 : o1;
        float v = sel * __builtin_amdgcn_rcpf(nrm);
        v *= __shfl_xor(v, 1, 64);
        v *= __shfl_xor(v, 2, 64);
        v *= __shfl_xor(v, 4, 64);
        v *= __shfl_xor(v, 8, 64);
        v *= __shfl_xor(v, 16, 64);
        v *= __shfl_xor(v, 32, 64);
        if (lane == 0) out[n0 + m] = v;
    }
}

// ---- fallback if ws too small ----
__global__ __launch_bounds__(256) void qnade_fallback(
    const float* __restrict__ x, const float* __restrict__ W1,
    const float* __restrict__ b1, const float* __restrict__ W2,
    const float* __restrict__ b2, float* __restrict__ out)
{
    __shared__ __align__(16) float w20s[HD];
    __shared__ __align__(16) float w21s[HD];
    const int tid = threadIdx.x;
    for (int i = tid; i < HD; i += 256) {
        float2 w = ((const float2*)W2)[i];
        w20s[i] = w.x;
        w21s[i] = w.y;
    }
    const int lane = tid & 63;
    const int wv   = tid >> 6;
    const int n    = (blockIdx.x << 2) + wv;
    const float b20 = b2[0];
    const float b21 = b2[1];
    const float xv = x[n * DS + lane];
    float4 a[16];
    const float4* b1v = (const float4*)b1;
    #pragma unroll
    for (int q = 0; q < 16; ++q) a[q] = b1v[q * 64 + lane];
    __syncthreads();
    const float4* w20v = (const float4*)w20s;
    const float4* w21v = (const float4*)w21s;
    float wav = 1.0f;
    for (int d = 0; d < DS; ++d) {
        const float xd = __shfl(xv, d, 64);
        const float4* w1v = (const float4*)(W1 + d * HD);
        float dot0 = 0.0f, dot1 = 0.0f;
        #pragma unroll
        for (int q = 0; q < 16; ++q) {
            float4 w1 = w1v[q * 64 + lane];
            float4 av = a[q];
            float h0 = fast_tanh(av.x);
            float h1 = fast_tanh(av.y);
            float h2 = fast_tanh(av.z);
            float h3 = fast_tanh(av.w);
            float4 c0 = w20v[q * 64 + lane];
            float4 c1 = w21v[q * 64 + lane];
            dot0 = fmaf(h0, c0.x, dot0); dot0 = fmaf(h1, c0.y, dot0);
            dot0 = fmaf(h2, c0.z, dot0); dot0 = fmaf(h3, c0.w, dot0);
            dot1 = fmaf(h0, c1.x, dot1); dot1 = fmaf(h1, c1.y, dot1);
            dot1 = fmaf(h2, c1.z, dot1); dot1 = fmaf(h3, c1.w, dot1);
            av.x = fmaf(xd, w1.x, av.x); av.y = fmaf(xd, w1.y, av.y);
            av.z = fmaf(xd, w1.z, av.z); av.w = fmaf(xd, w1.w, av.w);
            a[q] = av;
        }
        #pragma unroll
        for (int m = 1; m < 64; m <<= 1) {
            dot0 += __shfl_xor(dot0, m, 64);
            dot1 += __shfl_xor(dot1, m, 64);
        }
        float o0 = fast_tanh(dot0 + b20);
        float o1 = fast_tanh(dot1 + b21);
        float nrm = sqrtf(fmaf(o0, o0, o1 * o1));
        nrm = fmaxf(nrm, 1e-12f);
        float sel = (xd > 0.0f) ? o0 : o1;
        wav *= sel / nrm;
    }
    out[n] = wav;
}

extern "C" void kernel_launch(void* const* d_in, const int* in_sizes, int n_in,
                              void* d_out, int out_size, void* d_ws, size_t ws_size,
                              hipStream_t stream) {
    const float* x  = (const float*)d_in[0];
    const float* W1 = (const float*)d_in[1];
    const float* b1 = (const float*)d_in[2];
    const float* W2 = (const float*)d_in[3];
    const float* b2 = (const float*)d_in[4];
    float* out = (float*)d_out;

    const size_t need = (size_t)(2 * DS * HD + 2) * sizeof(float);
    if (ws_size >= need) {
        float* Et  = (float*)d_ws;           // [2][DS][HD]
        float* C01 = Et + 2 * DS * HD;
        hipLaunchKernelGGL(qnade_prep_E, dim3(DS * HD / 256), dim3(256), 0, stream, W1, Et);
        hipLaunchKernelGGL(qnade_prep_S, dim3(1), dim3(256), 0, stream, W2, b2, C01);
        hipLaunchKernelGGL(qnade_main, dim3(NS / SPB), dim3(256), 0, stream, x, b1, W2, Et, C01, out);
    } else {
        hipLaunchKernelGGL(qnade_fallback, dim3(NS / 4), dim3(256), 0, stream, x, W1, b1, W2, b2, out);
    }
}

// Round 8
// 417.009 us; speedup vs baseline: 1.0865x; 1.0865x over previous
//
#include <hip/hip_runtime.h>
#include <math.h>

#define NS 8192
#define DS 64
#define HD 4096
#define C2L 2.8853900817779268f   // 2*log2(e)
#define CH 8                      // steps per chunk
#define NCH (DS / CH)

typedef float v2f __attribute__((ext_vector_type(2)));

__device__ __forceinline__ v2f pk_add(v2f a, v2f b) {
    v2f d; asm("v_pk_add_f32 %0, %1, %2" : "=v"(d) : "v"(a), "v"(b)); return d;
}
__device__ __forceinline__ v2f pk_mul(v2f a, v2f b) {
    v2f d; asm("v_pk_mul_f32 %0, %1, %2" : "=v"(d) : "v"(a), "v"(b)); return d;
}
__device__ __forceinline__ v2f pk_fma(v2f a, v2f b, v2f c) {
    v2f d; asm("v_pk_fma_f32 %0, %1, %2, %3" : "=v"(d) : "v"(a), "v"(b), "v"(c)); return d;
}

__device__ __forceinline__ float fast_tanh(float x) {
    float t = __builtin_amdgcn_exp2f(x * C2L);
    float r = __builtin_amdgcn_rcpf(t + 1.0f);
    return __builtin_fmaf(-2.0f, r, 1.0f);
}

template <int PATT>
__device__ __forceinline__ v2f swz_xor(v2f v) {
    v2f d;
    d.x = __int_as_float(__builtin_amdgcn_ds_swizzle(__float_as_int(v.x), PATT));
    d.y = __int_as_float(__builtin_amdgcn_ds_swizzle(__float_as_int(v.y), PATT));
    return d;
}

// ---- setup: Et[0][d][h]=e^{+2W1}, Et[1][d][h]=e^{-2W1}; C01 = colsum(W2)+b2 ----
__global__ __launch_bounds__(256) void qnade_prep_E(
    const float* __restrict__ W1, float* __restrict__ Et)
{
    int i = blockIdx.x * 256 + threadIdx.x;
    float w = W1[i] * C2L;
    Et[i]           = __builtin_amdgcn_exp2f(w);
    Et[DS * HD + i] = __builtin_amdgcn_exp2f(-w);
}

__global__ __launch_bounds__(256) void qnade_prep_S(
    const float* __restrict__ W2, const float* __restrict__ b2, float* __restrict__ C01)
{
    __shared__ float p0[4], p1[4];
    int tid = threadIdx.x;
    float s0 = 0.0f, s1 = 0.0f;
    for (int h = tid; h < HD; h += 256) {
        float2 w = ((const float2*)W2)[h];
        s0 += w.x; s1 += w.y;
    }
    #pragma unroll
    for (int m = 1; m < 64; m <<= 1) {
        s0 += __shfl_xor(s0, m, 64);
        s1 += __shfl_xor(s1, m, 64);
    }
    if ((tid & 63) == 0) { p0[tid >> 6] = s0; p1[tid >> 6] = s1; }
    __syncthreads();
    if (tid == 0) {
        C01[0] = p0[0] + p0[1] + p0[2] + p0[3] + b2[0];
        C01[1] = p1[0] + p1[1] + p1[2] + p1[3] + b2[1];
    }
}

// ---- main: one block = 2 samples; each wave owns a 1024-elem quarter and runs
// TWO independent Montgomery/dot chains per step (2x in-wave ILP). W2 regs
// shared across samples. Round-6 skeleton otherwise (1 LDS store per sample
// per step, chunked deferred reduce, deferred epilogue).
__global__ __launch_bounds__(256, 3) void qnade_main(
    const float* __restrict__ x, const float* __restrict__ b1,
    const float* __restrict__ W2, const float* __restrict__ Et,
    const float* __restrict__ C01, float* __restrict__ out)
{
    __shared__ float2 parts[2][CH][256];   // 32 KB
    __shared__ float2 fin[2][DS];          // 1 KB

    const int tid  = threadIdx.x;
    const int lane = tid & 63;
    const int wv   = tid >> 6;
    const int n0   = blockIdx.x * 2;
    const int hbase = wv * 1024 + lane * 4;   // + q*256 + c

    // W2 columns as (even,odd)-element pairs — shared by both samples
    v2f w20[8], w21[8];
    #pragma unroll
    for (int q = 0; q < 4; ++q) {
        const float4* p = (const float4*)(W2 + 2 * (hbase + q * 256));
        float4 A = p[0], B = p[1];
        w20[2*q]   = (v2f){A.x, A.z};  w21[2*q]   = (v2f){A.y, A.w};
        w20[2*q+1] = (v2f){B.x, B.z};  w21[2*q+1] = (v2f){B.y, B.w};
    }

    // t0 = e^{2*b1}, identical start for both samples
    v2f ta[8], tb[8];
    #pragma unroll
    for (int q = 0; q < 4; ++q) {
        float4 b = *(const float4*)(b1 + hbase + q * 256);
        v2f v0 = (v2f){__builtin_amdgcn_exp2f(b.x * C2L), __builtin_amdgcn_exp2f(b.y * C2L)};
        v2f v1 = (v2f){__builtin_amdgcn_exp2f(b.z * C2L), __builtin_amdgcn_exp2f(b.w * C2L)};
        ta[2*q] = v0; tb[2*q] = v0;
        ta[2*q+1] = v1; tb[2*q+1] = v1;
    }

    const unsigned long long mska = __ballot(x[n0 * DS + lane] > 0.0f);
    const unsigned long long mskb = __ballot(x[(n0 + 1) * DS + lane] > 0.0f);
    const v2f one = (v2f){1.0f, 1.0f};

    int d = 0;
    for (int c = 0; c < NCH; ++c) {
        #pragma unroll 2
        for (int s8 = 0; s8 < CH; ++s8, ++d) {
            const unsigned rowoff = (unsigned)d * HD;
            const unsigned ua = (((mska >> d) & 1ull) ? 0u : (unsigned)(DS * HD)) + rowoff;
            const unsigned ub = (((mskb >> d) & 1ull) ? 0u : (unsigned)(DS * HD)) + rowoff;
            const float* Ea = Et + ua + hbase;
            const float* Eb = Et + ub + hbase;
            float4 ea0 = *(const float4*)(Ea);
            float4 ea1 = *(const float4*)(Ea + 256);
            float4 ea2 = *(const float4*)(Ea + 512);
            float4 ea3 = *(const float4*)(Ea + 768);
            float4 eb0 = *(const float4*)(Eb);
            float4 eb1 = *(const float4*)(Eb + 256);
            float4 eb2 = *(const float4*)(Eb + 512);
            float4 eb3 = *(const float4*)(Eb + 768);

            // ---- sample A: prefix, rcp, fused recovery+dot ----
            v2f pa[8];
            pa[0] = pk_add(ta[0], one);
            #pragma unroll
            for (int j = 1; j < 8; ++j) pa[j] = pk_fma(pa[j - 1], ta[j], pa[j - 1]);
            float Pa = pa[7].x * pa[7].y;
            float Ra = __builtin_amdgcn_rcpf(Pa);
            v2f RA = (v2f){Ra * pa[7].y, Ra * pa[7].x};
            v2f a0, a1;
            {
                v2f r = pk_mul(RA, pa[6]);
                a0 = pk_mul(r, w20[7]);
                a1 = pk_mul(r, w21[7]);
                RA = pk_fma(RA, ta[7], RA);
            }
            #pragma unroll
            for (int j = 6; j >= 1; --j) {
                v2f r = pk_mul(RA, pa[j - 1]);
                a0 = pk_fma(r, w20[j], a0);
                a1 = pk_fma(r, w21[j], a1);
                RA = pk_fma(RA, ta[j], RA);
            }
            a0 = pk_fma(RA, w20[0], a0);
            a1 = pk_fma(RA, w21[0], a1);

            // ---- sample B ----
            v2f pb[8];
            pb[0] = pk_add(tb[0], one);
            #pragma unroll
            for (int j = 1; j < 8; ++j) pb[j] = pk_fma(pb[j - 1], tb[j], pb[j - 1]);
            float Pb = pb[7].x * pb[7].y;
            float Rb = __builtin_amdgcn_rcpf(Pb);
            v2f RB = (v2f){Rb * pb[7].y, Rb * pb[7].x};
            v2f b0, b1a;
            {
                v2f r = pk_mul(RB, pb[6]);
                b0 = pk_mul(r, w20[7]);
                b1a = pk_mul(r, w21[7]);
                RB = pk_fma(RB, tb[7], RB);
            }
            #pragma unroll
            for (int j = 6; j >= 1; --j) {
                v2f r = pk_mul(RB, pb[j - 1]);
                b0 = pk_fma(r, w20[j], b0);
                b1a = pk_fma(r, w21[j], b1a);
                RB = pk_fma(RB, tb[j], RB);
            }
            b0 = pk_fma(RB, w20[0], b0);
            b1a = pk_fma(RB, w21[0], b1a);

            // ---- advance both states ----
            ta[0] = pk_mul(ta[0], (v2f){ea0.x, ea0.y});
            ta[1] = pk_mul(ta[1], (v2f){ea0.z, ea0.w});
            ta[2] = pk_mul(ta[2], (v2f){ea1.x, ea1.y});
            ta[3] = pk_mul(ta[3], (v2f){ea1.z, ea1.w});
            ta[4] = pk_mul(ta[4], (v2f){ea2.x, ea2.y});
            ta[5] = pk_mul(ta[5], (v2f){ea2.z, ea2.w});
            ta[6] = pk_mul(ta[6], (v2f){ea3.x, ea3.y});
            ta[7] = pk_mul(ta[7], (v2f){ea3.z, ea3.w});
            tb[0] = pk_mul(tb[0], (v2f){eb0.x, eb0.y});
            tb[1] = pk_mul(tb[1], (v2f){eb0.z, eb0.w});
            tb[2] = pk_mul(tb[2], (v2f){eb1.x, eb1.y});
            tb[3] = pk_mul(tb[3], (v2f){eb1.z, eb1.w});
            tb[4] = pk_mul(tb[4], (v2f){eb2.x, eb2.y});
            tb[5] = pk_mul(tb[5], (v2f){eb2.z, eb2.w});
            tb[6] = pk_mul(tb[6], (v2f){eb3.x, eb3.y});
            tb[7] = pk_mul(tb[7], (v2f){eb3.z, eb3.w});

            // one LDS store per sample per step; 2-way bank alias = free
            parts[0][s8][tid] = make_float2(a0.x + a0.y, a1.x + a1.y);
            parts[1][s8][tid] = make_float2(b0.x + b0.y, b1a.x + b1a.y);
        }

        __syncthreads();
        // chunk reduce: 16 (sample,step) units x 256 partials; 16 threads/unit
        {
            const int j  = tid & 15;
            const int u  = tid >> 4;
            const int m  = u & 1;
            const int sr = u >> 1;
            v2f s = (v2f){0.0f, 0.0f};
            #pragma unroll
            for (int i = 0; i < 16; ++i) {
                float2 v = parts[m][sr][j + 16 * i];
                s = pk_add(s, (v2f){v.x, v.y});
            }
            s = pk_add(s, swz_xor<0x041F>(s));   // xor 1
            s = pk_add(s, swz_xor<0x081F>(s));   // xor 2
            s = pk_add(s, swz_xor<0x101F>(s));   // xor 4
            s = pk_add(s, swz_xor<0x201F>(s));   // xor 8
            if (j == 0) fin[m][c * CH + sr] = make_float2(s.x, s.y);
        }
        __syncthreads();
    }

    // deferred epilogue: wave 0 -> sample A, wave 1 -> sample B; lane = step
    if (wv < 2) {
        const unsigned long long mm = wv ? mskb : mska;
        float2 sv = fin[wv][lane];
        float dot0 = __builtin_fmaf(-2.0f, sv.x, C01[0]);
        float dot1 = __builtin_fmaf(-2.0f, sv.y, C01[1]);
        float o0 = fast_tanh(dot0);
        float o1 = fast_tanh(dot1);
        float nrm = sqrtf(__builtin_fmaf(o0, o0, o1 * o1));
        nrm = fmaxf(nrm, 1e-12f);
        float sel = ((mm >> lane) & 1ull) ? o0 : o1;
        float v = sel * __builtin_amdgcn_rcpf(nrm);
        v *= __shfl_xor(v, 1, 64);
        v *= __shfl_xor(v, 2, 64);
        v *= __shfl_xor(v, 4, 64);
        v *= __shfl_xor(v, 8, 64);
        v *= __shfl_xor(v, 16, 64);
        v *= __shfl_xor(v, 32, 64);
        if (lane == 0) out[n0 + wv] = v;
    }
}

// ---- fallback if ws too small ----
__global__ __launch_bounds__(256) void qnade_fallback(
    const float* __restrict__ x, const float* __restrict__ W1,
    const float* __restrict__ b1, const float* __restrict__ W2,
    const float* __restrict__ b2, float* __restrict__ out)
{
    __shared__ __align__(16) float w20s[HD];
    __shared__ __align__(16) float w21s[HD];
    const int tid = threadIdx.x;
    for (int i = tid; i < HD; i += 256) {
        float2 w = ((const float2*)W2)[i];
        w20s[i] = w.x;
        w21s[i] = w.y;
    }
    const int lane = tid & 63;
    const int wv   = tid >> 6;
    const int n    = (blockIdx.x << 2) + wv;
    const float b20 = b2[0];
    const float b21 = b2[1];
    const float xv = x[n * DS + lane];
    float4 a[16];
    const float4* b1v = (const float4*)b1;
    #pragma unroll
    for (int q = 0; q < 16; ++q) a[q] = b1v[q * 64 + lane];
    __syncthreads();
    const float4* w20v = (const float4*)w20s;
    const float4* w21v = (const float4*)w21s;
    float wav = 1.0f;
    for (int d = 0; d < DS; ++d) {
        const float xd = __shfl(xv, d, 64);
        const float4* w1v = (const float4*)(W1 + d * HD);
        float dot0 = 0.0f, dot1 = 0.0f;
        #pragma unroll
        for (int q = 0; q < 16; ++q) {
            float4 w1 = w1v[q * 64 + lane];
            float4 av = a[q];
            float h0 = fast_tanh(av.x);
            float h1 = fast_tanh(av.y);
            float h2 = fast_tanh(av.z);
            float h3 = fast_tanh(av.w);
            float4 c0 = w20v[q * 64 + lane];
            float4 c1 = w21v[q * 64 + lane];
            dot0 = fmaf(h0, c0.x, dot0); dot0 = fmaf(h1, c0.y, dot0);
            dot0 = fmaf(h2, c0.z, dot0); dot0 = fmaf(h3, c0.w, dot0);
            dot1 = fmaf(h0, c1.x, dot1); dot1 = fmaf(h1, c1.y, dot1);
            dot1 = fmaf(h2, c1.z, dot1); dot1 = fmaf(h3, c1.w, dot1);
            av.x = fmaf(xd, w1.x, av.x); av.y = fmaf(xd, w1.y, av.y);
            av.z = fmaf(xd, w1.z, av.z); av.w = fmaf(xd, w1.w, av.w);
            a[q] = av;
        }
        #pragma unroll
        for (int m = 1; m < 64; m <<= 1) {
            dot0 += __shfl_xor(dot0, m, 64);
            dot1 += __shfl_xor(dot1, m, 64);
        }
        float o0 = fast_tanh(dot0 + b20);
        float o1 = fast_tanh(dot1 + b21);
        float nrm = sqrtf(fmaf(o0, o0, o1 * o1));
        nrm = fmaxf(nrm, 1e-12f);
        float sel = (xd > 0.0f) ? o0 : o1;
        wav *= sel / nrm;
    }
    out[n] = wav;
}

extern "C" void kernel_launch(void* const* d_in, const int* in_sizes, int n_in,
                              void* d_out, int out_size, void* d_ws, size_t ws_size,
                              hipStream_t stream) {
    const float* x  = (const float*)d_in[0];
    const float* W1 = (const float*)d_in[1];
    const float* b1 = (const float*)d_in[2];
    const float* W2 = (const float*)d_in[3];
    const float* b2 = (const float*)d_in[4];
    float* out = (float*)d_out;

    const size_t need = (size_t)(2 * DS * HD + 2) * sizeof(float);
    if (ws_size >= need) {
        float* Et  = (float*)d_ws;           // [2][DS][HD]
        float* C01 = Et + 2 * DS * HD;
        hipLaunchKernelGGL(qnade_prep_E, dim3(DS * HD / 256), dim3(256), 0, stream, W1, Et);
        hipLaunchKernelGGL(qnade_prep_S, dim3(1), dim3(256), 0, stream, W2, b2, C01);
        hipLaunchKernelGGL(qnade_main, dim3(NS / 2), dim3(256), 0, stream, x, b1, W2, Et, C01, out);
    } else {
        hipLaunchKernelGGL(qnade_fallback, dim3(NS / 4), dim3(256), 0, stream, x, W1, b1, W2, b2, out);
    }
}